// Round 15
// baseline (109.534 us; speedup 1.0000x reference)
//
#include <hip/hip_runtime.h>

// x: (B=4, C=64, H=512, W=512) fp32 -> 131072 independent rows of 512 cols.
// FIR: f[j] = sum_k a[k]*x[j-2+k] (SAME zero-pad), then IIR:
//   y[j] = f[j] - (v0*y[j-3] + v1*y[j-2] + v2*y[j-1]), zero initial state.
//
// R15 = R13 + two synergistic changes:
//  (a) halo-via-shuffle: each thread loads only its OWN 4 f4 (no overlap,
//      no bounds checks); the 2 halo f4s (left g=4s-1, right g=4s+4) come
//      from neighbor lanes via 8 ds_bpermute (DS ops measured ~1-2cyc eff).
//      Cuts load instructions 6->4 and request overlap 1.5x -> 1.0x, and
//      frees ~8 VGPRs of live state.
//  (b) __launch_bounds__(256,8): 8 waves/SIMD (VGPR cap 64) for +33% TLP.
//
//   thread = (row, 16-col segment); 8 rows x 32 segs = 256 threads/block.
//   phase1: particular solution y_p over 16 cols (zero entry state)
//   scan  : Hillis-Steele affine scan over 32 segments per 32-lane group
//   fixup : w[k] recursion from s_enter, y[k] += w[k]   (no LDS)
//   stores: shuffle-transposed, 4 coalesced full-line float4 per thread.

constexpr int Wd    = 512;
constexpr int TROWS = 8;
constexpr int NT    = 256;
constexpr int F4ROW = Wd / 4;   // 128

__global__ __launch_bounds__(NT, 8)
void iir_conv2d_kernel(const float4* __restrict__ x4,
                       const float* __restrict__ w1,   // (C,1,5)
                       const float* __restrict__ w2,   // (C,3)
                       float4* __restrict__ y4)
{
    __shared__ float H[3][16];   // H[j][k]: y[k] response to unit entry state e_j

    const int tid  = threadIdx.x;
    const int lane = tid & 63;
    const int r    = tid >> 5;          // row within block (0..7)
    const int s    = tid & 31;          // 16-col segment (0..31)
    const int row0 = blockIdx.x * TROWS;   // 8 | 512 -> channel uniform per block
    const int row  = row0 + r;
    const int c    = (row0 >> 9) & 63;

    // taps (wave-uniform, L1 broadcast)
    const float a0 = w1[c*5+0], a1 = w1[c*5+1], a2 = w1[c*5+2],
                a3 = w1[c*5+3], a4 = w1[c*5+4];
    const float v0 = w2[c*3+0], v1 = w2[c*3+1], v2 = w2[c*3+2];

    // ---- loads: exactly this thread's 4 f4 (cols 16s..16s+15), no overlap ----
    const float4* __restrict__ xr = x4 + (size_t)row * F4ROW;
    float4 xv0 = xr[4*s+0], xv1 = xr[4*s+1], xv2 = xr[4*s+2], xv3 = xr[4*s+3];

    // ---- H table: 3 threads, 16-step recursions (overlaps load latency) ----
    if (tid < 3) {
        const int j = tid;
        float h3 = (j==0) ? 1.f : 0.f;
        float h2 = (j==1) ? 1.f : 0.f;
        float h1 = (j==2) ? 1.f : 0.f;
        #pragma unroll
        for (int k = 0; k < 16; ++k) {
            const float n = -(v0*h3 + v1*h2 + v2*h1);
            H[j][k] = n;
            h3 = h2; h2 = h1; h1 = n;
        }
    }

    // ---- halo exchange: left f4 = lane-1's xv3, right f4 = lane+1's xv0 ----
    float xw[24];
    {
        const int srcL = (s >= 1)  ? (lane - 1) : lane;
        const int srcR = (s <= 30) ? (lane + 1) : lane;
        float l0 = __shfl(xv3.x, srcL, 64);
        float l1 = __shfl(xv3.y, srcL, 64);
        float l2 = __shfl(xv3.z, srcL, 64);
        float l3 = __shfl(xv3.w, srcL, 64);
        float r0 = __shfl(xv0.x, srcR, 64);
        float r1 = __shfl(xv0.y, srcR, 64);
        float r2 = __shfl(xv0.z, srcR, 64);
        float r3 = __shfl(xv0.w, srcR, 64);
        if (s == 0)  { l0 = 0.f; l1 = 0.f; l2 = 0.f; l3 = 0.f; }
        if (s == 31) { r0 = 0.f; r1 = 0.f; r2 = 0.f; r3 = 0.f; }
        xw[0]=l0;  xw[1]=l1;  xw[2]=l2;  xw[3]=l3;
        xw[4]=xv0.x;  xw[5]=xv0.y;  xw[6]=xv0.z;  xw[7]=xv0.w;
        xw[8]=xv1.x;  xw[9]=xv1.y;  xw[10]=xv1.z; xw[11]=xv1.w;
        xw[12]=xv2.x; xw[13]=xv2.y; xw[14]=xv2.z; xw[15]=xv2.w;
        xw[16]=xv3.x; xw[17]=xv3.y; xw[18]=xv3.z; xw[19]=xv3.w;
        xw[20]=r0; xw[21]=r1; xw[22]=r2; xw[23]=r3;
    }

    // ---- phase 1: particular solution (zero entry state) ----
    float y[16];
    {
        float ym3 = 0.f, ym2 = 0.f, ym1 = 0.f;
        #pragma unroll
        for (int k = 0; k < 16; ++k) {
            // col 16s+k needs x[col-2..col+2] = xw[k+2..k+6]
            const float f = a0*xw[k+2] + a1*xw[k+3] + a2*xw[k+4]
                          + a3*xw[k+5] + a4*xw[k+6];
            const float t = v0*ym3 + v1*ym2;      // off the serial chain
            const float yy = (f - t) - v2*ym1;
            y[k] = yy;
            ym3 = ym2; ym2 = ym1; ym1 = yy;
        }
    }

    __syncthreads();   // H ready (the only barrier)

    // ---- T = 16-step state transform: T[i][j] = H[j][13+i] ----
    float M[3][3];
    #pragma unroll
    for (int i = 0; i < 3; ++i)
        #pragma unroll
        for (int j = 0; j < 3; ++j) M[i][j] = H[j][13+i];

    // ---- affine scan over 32 segments (within each 32-lane group) ----
    float b0 = y[13], b1 = y[14], b2 = y[15];
    #pragma unroll
    for (int rd = 0; rd < 5; ++rd) {
        const int d = 1 << rd;
        const int src = (s >= d) ? (lane - d) : lane;
        const float g0 = __shfl(b0, src, 64);
        const float g1 = __shfl(b1, src, 64);
        const float g2 = __shfl(b2, src, 64);
        if (s >= d) {
            b0 += M[0][0]*g0 + M[0][1]*g1 + M[0][2]*g2;
            b1 += M[1][0]*g0 + M[1][1]*g1 + M[1][2]*g2;
            b2 += M[2][0]*g0 + M[2][1]*g1 + M[2][2]*g2;
        }
        if (rd < 4) {   // M <- M*M for the next round
            float N[3][3];
            #pragma unroll
            for (int i = 0; i < 3; ++i)
                #pragma unroll
                for (int j = 0; j < 3; ++j)
                    N[i][j] = M[i][0]*M[0][j] + M[i][1]*M[1][j] + M[i][2]*M[2][j];
            #pragma unroll
            for (int i = 0; i < 3; ++i)
                #pragma unroll
                for (int j = 0; j < 3; ++j) M[i][j] = N[i][j];
        }
    }

    // ---- entering state = inclusive scan of previous segment ----
    // fixup via in-register recursion, no LDS.
    {
        const int src = (s >= 1) ? (lane - 1) : lane;
        float wm3 = __shfl(b0, src, 64);
        float wm2 = __shfl(b1, src, 64);
        float wm1 = __shfl(b2, src, 64);
        if (s == 0) { wm3 = 0.f; wm2 = 0.f; wm1 = 0.f; }
        #pragma unroll
        for (int k = 0; k < 16; ++k) {
            const float w = -(v0*wm3 + v1*wm2 + v2*wm1);
            y[k] += w;
            wm3 = wm2; wm2 = wm1; wm1 = w;
        }
    }

    // ---- store: shuffle-transpose then coalesced full-line float4 stores ----
    // Instr u: lane i (i=lane&31) stores f4 idx 32u+i of its row
    //   -> floats 128u+4i+m, owned by src lane 8u+(i>>2), reg 4*(i&3)+m.
    float4* __restrict__ yrow = y4 + (size_t)row * F4ROW;
    #pragma unroll
    for (int u = 0; u < 4; ++u) {
        const int srcl = (lane & 32) | (8*u + ((lane & 31) >> 2));
        float out0, out1, out2, out3;
        #pragma unroll
        for (int q = 0; q < 4; ++q) {
            const float t0 = __shfl(y[4*q+0], srcl, 64);
            const float t1 = __shfl(y[4*q+1], srcl, 64);
            const float t2 = __shfl(y[4*q+2], srcl, 64);
            const float t3 = __shfl(y[4*q+3], srcl, 64);
            if ((lane & 3) == q) { out0 = t0; out1 = t1; out2 = t2; out3 = t3; }
        }
        float4 o; o.x = out0; o.y = out1; o.z = out2; o.w = out3;
        yrow[32*u + (lane & 31)] = o;
    }
}

extern "C" void kernel_launch(void* const* d_in, const int* in_sizes, int n_in,
                              void* d_out, int out_size, void* d_ws, size_t ws_size,
                              hipStream_t stream) {
    const float4* x4 = (const float4*)d_in[0];
    const float*  w1 = (const float*)d_in[1];
    const float*  w2 = (const float*)d_in[2];
    float4* y4 = (float4*)d_out;

    const int nrows  = out_size / Wd;        // 131072
    const int blocks = nrows / TROWS;        // 16384
    iir_conv2d_kernel<<<blocks, NT, 0, stream>>>(x4, w1, w2, y4);
}

// Round 16
// 99.562 us; speedup vs baseline: 1.1002x; 1.1002x over previous
//
#include <hip/hip_runtime.h>

// x: (B=4, C=64, H=512, W=512) fp32 -> 131072 independent rows of 512 cols.
// FIR: f[j] = sum_k a[k]*x[j-2+k] (SAME zero-pad), then IIR:
//   y[j] = f[j] - (v0*y[j-3] + v1*y[j-2] + v2*y[j-1]), zero initial state.
//
// R16 = R13 + ONLY R15's change (a), at the proven 6-wave occupancy:
//   halo-via-shuffle: each thread loads only its OWN 4 f4 (no overlap, no
//   bounds checks); the 2 halo f4s come from neighbor lanes via 8 shuffles.
//   Cuts per-wave load line-requests ~204 -> ~136 and frees ~2 live f4s.
// (R15 bundled this with a 64-VGPR 8-wave cap and regressed; this round
//  isolates (a).)
//
//   thread = (row, 16-col segment); 8 rows x 32 segs = 256 threads/block.
//   phase1: particular solution y_p over 16 cols (zero entry state)
//   scan  : Hillis-Steele affine scan over 32 segments per 32-lane group
//   fixup : w[k] recursion from s_enter, y[k] += w[k]   (no LDS)
//   stores: shuffle-transposed, 4 coalesced full-line float4 per thread.

constexpr int Wd    = 512;
constexpr int TROWS = 8;
constexpr int NT    = 256;
constexpr int F4ROW = Wd / 4;   // 128

__global__ __launch_bounds__(NT, 6)
void iir_conv2d_kernel(const float4* __restrict__ x4,
                       const float* __restrict__ w1,   // (C,1,5)
                       const float* __restrict__ w2,   // (C,3)
                       float4* __restrict__ y4)
{
    __shared__ float H[3][16];   // H[j][k]: y[k] response to unit entry state e_j

    const int tid  = threadIdx.x;
    const int lane = tid & 63;
    const int r    = tid >> 5;          // row within block (0..7)
    const int s    = tid & 31;          // 16-col segment (0..31)
    const int row0 = blockIdx.x * TROWS;   // 8 | 512 -> channel uniform per block
    const int row  = row0 + r;
    const int c    = (row0 >> 9) & 63;

    // taps (wave-uniform, L1 broadcast)
    const float a0 = w1[c*5+0], a1 = w1[c*5+1], a2 = w1[c*5+2],
                a3 = w1[c*5+3], a4 = w1[c*5+4];
    const float v0 = w2[c*3+0], v1 = w2[c*3+1], v2 = w2[c*3+2];

    // ---- loads: exactly this thread's 4 f4 (cols 16s..16s+15), no overlap ----
    const float4* __restrict__ xr = x4 + (size_t)row * F4ROW;
    float4 xv0 = xr[4*s+0], xv1 = xr[4*s+1], xv2 = xr[4*s+2], xv3 = xr[4*s+3];

    // ---- H table: 3 threads, 16-step recursions (overlaps load latency) ----
    if (tid < 3) {
        const int j = tid;
        float h3 = (j==0) ? 1.f : 0.f;
        float h2 = (j==1) ? 1.f : 0.f;
        float h1 = (j==2) ? 1.f : 0.f;
        #pragma unroll
        for (int k = 0; k < 16; ++k) {
            const float n = -(v0*h3 + v1*h2 + v2*h1);
            H[j][k] = n;
            h3 = h2; h2 = h1; h1 = n;
        }
    }

    // ---- halo exchange: left f4 = lane-1's xv3, right f4 = lane+1's xv0 ----
    float xw[24];
    {
        const int srcL = (s >= 1)  ? (lane - 1) : lane;
        const int srcR = (s <= 30) ? (lane + 1) : lane;
        float l0 = __shfl(xv3.x, srcL, 64);
        float l1 = __shfl(xv3.y, srcL, 64);
        float l2 = __shfl(xv3.z, srcL, 64);
        float l3 = __shfl(xv3.w, srcL, 64);
        float r0 = __shfl(xv0.x, srcR, 64);
        float r1 = __shfl(xv0.y, srcR, 64);
        float r2 = __shfl(xv0.z, srcR, 64);
        float r3 = __shfl(xv0.w, srcR, 64);
        if (s == 0)  { l0 = 0.f; l1 = 0.f; l2 = 0.f; l3 = 0.f; }
        if (s == 31) { r0 = 0.f; r1 = 0.f; r2 = 0.f; r3 = 0.f; }
        xw[0]=l0;  xw[1]=l1;  xw[2]=l2;  xw[3]=l3;
        xw[4]=xv0.x;  xw[5]=xv0.y;  xw[6]=xv0.z;  xw[7]=xv0.w;
        xw[8]=xv1.x;  xw[9]=xv1.y;  xw[10]=xv1.z; xw[11]=xv1.w;
        xw[12]=xv2.x; xw[13]=xv2.y; xw[14]=xv2.z; xw[15]=xv2.w;
        xw[16]=xv3.x; xw[17]=xv3.y; xw[18]=xv3.z; xw[19]=xv3.w;
        xw[20]=r0; xw[21]=r1; xw[22]=r2; xw[23]=r3;
    }

    // ---- phase 1: particular solution (zero entry state) ----
    float y[16];
    {
        float ym3 = 0.f, ym2 = 0.f, ym1 = 0.f;
        #pragma unroll
        for (int k = 0; k < 16; ++k) {
            // col 16s+k needs x[col-2..col+2] = xw[k+2..k+6]
            const float f = a0*xw[k+2] + a1*xw[k+3] + a2*xw[k+4]
                          + a3*xw[k+5] + a4*xw[k+6];
            const float t = v0*ym3 + v1*ym2;      // off the serial chain
            const float yy = (f - t) - v2*ym1;
            y[k] = yy;
            ym3 = ym2; ym2 = ym1; ym1 = yy;
        }
    }

    __syncthreads();   // H ready (the only barrier)

    // ---- T = 16-step state transform: T[i][j] = H[j][13+i] ----
    float M[3][3];
    #pragma unroll
    for (int i = 0; i < 3; ++i)
        #pragma unroll
        for (int j = 0; j < 3; ++j) M[i][j] = H[j][13+i];

    // ---- affine scan over 32 segments (within each 32-lane group) ----
    float b0 = y[13], b1 = y[14], b2 = y[15];
    #pragma unroll
    for (int rd = 0; rd < 5; ++rd) {
        const int d = 1 << rd;
        const int src = (s >= d) ? (lane - d) : lane;
        const float g0 = __shfl(b0, src, 64);
        const float g1 = __shfl(b1, src, 64);
        const float g2 = __shfl(b2, src, 64);
        if (s >= d) {
            b0 += M[0][0]*g0 + M[0][1]*g1 + M[0][2]*g2;
            b1 += M[1][0]*g0 + M[1][1]*g1 + M[1][2]*g2;
            b2 += M[2][0]*g0 + M[2][1]*g1 + M[2][2]*g2;
        }
        if (rd < 4) {   // M <- M*M for the next round
            float N[3][3];
            #pragma unroll
            for (int i = 0; i < 3; ++i)
                #pragma unroll
                for (int j = 0; j < 3; ++j)
                    N[i][j] = M[i][0]*M[0][j] + M[i][1]*M[1][j] + M[i][2]*M[2][j];
            #pragma unroll
            for (int i = 0; i < 3; ++i)
                #pragma unroll
                for (int j = 0; j < 3; ++j) M[i][j] = N[i][j];
        }
    }

    // ---- entering state = inclusive scan of previous segment ----
    // fixup via in-register recursion, no LDS.
    {
        const int src = (s >= 1) ? (lane - 1) : lane;
        float wm3 = __shfl(b0, src, 64);
        float wm2 = __shfl(b1, src, 64);
        float wm1 = __shfl(b2, src, 64);
        if (s == 0) { wm3 = 0.f; wm2 = 0.f; wm1 = 0.f; }
        #pragma unroll
        for (int k = 0; k < 16; ++k) {
            const float w = -(v0*wm3 + v1*wm2 + v2*wm1);
            y[k] += w;
            wm3 = wm2; wm2 = wm1; wm1 = w;
        }
    }

    // ---- store: shuffle-transpose then coalesced full-line float4 stores ----
    // Instr u: lane i (i=lane&31) stores f4 idx 32u+i of its row
    //   -> floats 128u+4i+m, owned by src lane 8u+(i>>2), reg 4*(i&3)+m.
    float4* __restrict__ yrow = y4 + (size_t)row * F4ROW;
    #pragma unroll
    for (int u = 0; u < 4; ++u) {
        const int srcl = (lane & 32) | (8*u + ((lane & 31) >> 2));
        float out0, out1, out2, out3;
        #pragma unroll
        for (int q = 0; q < 4; ++q) {
            const float t0 = __shfl(y[4*q+0], srcl, 64);
            const float t1 = __shfl(y[4*q+1], srcl, 64);
            const float t2 = __shfl(y[4*q+2], srcl, 64);
            const float t3 = __shfl(y[4*q+3], srcl, 64);
            if ((lane & 3) == q) { out0 = t0; out1 = t1; out2 = t2; out3 = t3; }
        }
        float4 o; o.x = out0; o.y = out1; o.z = out2; o.w = out3;
        yrow[32*u + (lane & 31)] = o;
    }
}

extern "C" void kernel_launch(void* const* d_in, const int* in_sizes, int n_in,
                              void* d_out, int out_size, void* d_ws, size_t ws_size,
                              hipStream_t stream) {
    const float4* x4 = (const float4*)d_in[0];
    const float*  w1 = (const float*)d_in[1];
    const float*  w2 = (const float*)d_in[2];
    float4* y4 = (float4*)d_out;

    const int nrows  = out_size / Wd;        // 131072
    const int blocks = nrows / TROWS;        // 16384
    iir_conv2d_kernel<<<blocks, NT, 0, stream>>>(x4, w1, w2, y4);
}